// Round 12
// baseline (463.639 us; speedup 1.0000x reference)
//
#include <hip/hip_runtime.h>

// CustomFourierLayer: out[b,o] = sum_{i,k} coef[o,i,k] * f_k(x[b,i])
// R12: producer/consumer wave specialization. 6-wave blocks: waves 0-3
// consume (ds_read A + reg-load B + MFMA; fr=4 fc=2, BM=128 BN=256),
// waves 4-5 produce (genH -> As[buf^1]). Pipes (matrix/LDS/VALU/VMEM)
// run concurrently on DIFFERENT waves within each phase -- breaks the
// barrier-aligned homogeneous-wave serialization that pinned R8-R11 at
// MfmaUtil 38%. lgkmcnt is per-wave: consumers never wait on producer
// ds_writes except via the phase barrier. Phase = 4 i-cols, split-K x4.

#define O_COLS 1024
#define I_DIM  1024
#define NF33   33
#define B_ROWS 4096

#define CW2_BYTES  ((size_t)32 * 2048 * 512 * 2)   // 64 MiB, f16 frag blobs
#define XT_OFF     (CW2_BYTES)                      // 16 MiB f32 x^T
#define XT_BYTES   ((size_t)I_DIM * B_ROWS * 4)
#define BK_OFF     (XT_OFF + XT_BYTES)              // 4 MiB f32 bk32[i][o]
#define BK_BYTES   ((size_t)I_DIM * O_COLS * 4)
#define BIAS_OFF   (BK_OFF + BK_BYTES)              // 4 KiB
#define PART_OFF   (BIAS_OFF + (1 << 20))           // 3 x 16 MiB partials
#define PART_BYTES ((size_t)B_ROWS * O_COLS * 4)
#define NEED_T1    (PART_OFF + 3 * PART_BYTES)
#define NEED_T2    (BIAS_OFF + 4096)

#define ASTR 36    // A LDS row stride in f16 (72 B; 2-way bank aliasing = free)

typedef _Float16 half8 __attribute__((ext_vector_type(8)));
typedef float f32x16 __attribute__((ext_vector_type(16)));
typedef float float4v __attribute__((ext_vector_type(4)));
union H8 { half8 v; _Float16 h[8]; };

#define BAR() asm volatile("s_waitcnt lgkmcnt(0)\n\ts_barrier" ::: "memory")

// source k in coef's [sin1..16 | cos1..16 | 1] layout for interleaved feature f
__device__ __forceinline__ int ksrc_of(int f) {
  return (f >= 32) ? 32 : ((f >> 1) + ((f & 1) ? 16 : 0));
}

// ---------------------------------------------------------------------------
// coef f32 [o][i][k] -> Cw2 f16 in 32x32x16 B-fragment blobs + bk32[i][o]=k32.
// Blob (ob32, i*2+kcl) = 1KB: lane l = kh*32 + (o&31) holds 8 f16 = features
// kcl*16 + kh*8 + e of column i, output col o = ob32*32 + (l&31). (validated)
// ---------------------------------------------------------------------------
__global__ __launch_bounds__(256)
void convert_coef2(const float* __restrict__ coef, _Float16* __restrict__ Cw2,
                   float* __restrict__ bk) {
  const int gtid = blockIdx.x * 256 + threadIdx.x;   // 1M threads
  const int o = gtid & 1023;
  const int i = gtid >> 10;

  const float* src = coef + (size_t)o * (I_DIM * NF33) + (size_t)i * NF33;
  float r[NF33];
#pragma unroll
  for (int k = 0; k < NF33; ++k) r[k] = src[k];

  const int ob32 = o >> 5;
#pragma unroll
  for (int kcl = 0; kcl < 2; ++kcl) {
#pragma unroll
    for (int kh = 0; kh < 2; ++kh) {
      H8 h;
#pragma unroll
      for (int e = 0; e < 8; ++e)
        h.h[e] = (_Float16)r[ksrc_of(kcl * 16 + kh * 8 + e)];
      const size_t blob = (size_t)ob32 * 2048 + (size_t)i * 2 + kcl;
      *(half8*)(Cw2 + blob * 512 + (kh * 32 + (o & 31)) * 8) = h.v;
    }
  }
  bk[(size_t)i * 1024 + o] = r[32];
}

// x [4096][1024] -> xT [1024][4096]
__global__ __launch_bounds__(256)
void transpose_x(const float* __restrict__ x, float* __restrict__ xT) {
  __shared__ float t[64][65];
  const int bi = blockIdx.x;   // I-tile 0..15
  const int bj = blockIdx.y;   // B-tile 0..63
  const int tx = threadIdx.x & 63, ty = threadIdx.x >> 6;
#pragma unroll
  for (int mq = 0; mq < 16; ++mq) {
    const int r = mq * 4 + ty;
    t[r][tx] = x[(size_t)(bj * 64 + r) * I_DIM + bi * 64 + tx];
  }
  __syncthreads();
#pragma unroll
  for (int mq = 0; mq < 16; ++mq) {
    const int r = mq * 4 + ty;
    xT[(size_t)(bi * 64 + r) * B_ROWS + bj * 64 + tx] = t[tx][r];
  }
}

// bias[o] = sum_i bk[i][o]
__global__ __launch_bounds__(256)
void bias_from_bk(const float* __restrict__ bk, float* __restrict__ bias) {
  const int o = blockIdx.x * 256 + threadIdx.x;
  float s0 = 0.f, s1 = 0.f, s2 = 0.f, s3 = 0.f;
  for (int i = 0; i < 1024; i += 4) {
    s0 += bk[(size_t)i * 1024 + o];
    s1 += bk[(size_t)(i + 1) * 1024 + o];
    s2 += bk[(size_t)(i + 2) * 1024 + o];
    s3 += bk[(size_t)(i + 3) * 1024 + o];
  }
  bias[o] = (s0 + s1) + (s2 + s3);
}

// out += p0 + p1 + p2
__global__ __launch_bounds__(256)
void reduce_parts(float* __restrict__ out, const float* __restrict__ p0,
                  const float* __restrict__ p1, const float* __restrict__ p2) {
  const size_t i = ((size_t)blockIdx.x * 256 + threadIdx.x) * 4;
  float4v a = *(float4v*)(out + i);
  float4v b = *(const float4v*)(p0 + i);
  float4v c = *(const float4v*)(p1 + i);
  float4v d = *(const float4v*)(p2 + i);
  *(float4v*)(out + i) = a + b + c + d;
}

// doubling-tree harmonics 1..16 of xv -> 32 interleaved [sin,cos] f16 at dst
__device__ __forceinline__ void genH(float xv, _Float16* dst) {
  float S[17], C[17];
  __sincosf(xv, &S[1], &C[1]);
  S[2] = 2.f * S[1] * C[1];  C[2] = fmaf(-2.f * S[1], S[1], 1.f);
  S[3] = S[2] * C[1] + C[2] * S[1];  C[3] = C[2] * C[1] - S[2] * S[1];
  S[4] = 2.f * S[2] * C[2];  C[4] = fmaf(-2.f * S[2], S[2], 1.f);
  S[5] = S[4] * C[1] + C[4] * S[1];  C[5] = C[4] * C[1] - S[4] * S[1];
  S[6] = S[4] * C[2] + C[4] * S[2];  C[6] = C[4] * C[2] - S[4] * S[2];
  S[7] = S[4] * C[3] + C[4] * S[3];  C[7] = C[4] * C[3] - S[4] * S[3];
  S[8] = 2.f * S[4] * C[4];  C[8] = fmaf(-2.f * S[4], S[4], 1.f);
#pragma unroll
  for (int k = 1; k < 8; ++k) {
    S[8 + k] = S[8] * C[k] + C[8] * S[k];
    C[8 + k] = C[8] * C[k] - S[8] * S[k];
  }
  S[16] = 2.f * S[8] * C[8];  C[16] = fmaf(-2.f * S[8], S[8], 1.f);
#pragma unroll
  for (int c4 = 0; c4 < 4; ++c4) {
    H8 h;
#pragma unroll
    for (int q = 0; q < 4; ++q) {
      const int k = c4 * 4 + q + 1;
      h.h[2 * q] = (_Float16)S[k];  h.h[2 * q + 1] = (_Float16)C[k];
    }
    *(half8*)(dst + c4 * 8) = h.v;
  }
}

// ---------------------------------------------------------------------------
// GEMM, producer/consumer: 384 threads = 6 waves. Waves 0-3: consumers,
// wave wc covers cols o0+wc*64 (fc=2), rows m0..m0+128 (fr=4), acc 128.
// Waves 4-5: producers, genH 4 cols x 128 rows per phase into As[buf^1].
// Phase = 4 i-columns, one lgkm barrier per phase; B reg-loads cross it.
// ---------------------------------------------------------------------------
template <bool ATOMIC>
__global__ __launch_bounds__(384, 2)
void fourier_gemm10(const float* __restrict__ xT, const _Float16* __restrict__ Cw2,
                    const float* __restrict__ bias, float* __restrict__ out,
                    float* __restrict__ part) {
  __shared__ _Float16 As[2][4][128][ASTR];   // [buf][col][row][36], 73.7 KB

  const int tid = threadIdx.x, lane = tid & 63, wave = tid >> 6;   // 0..5

  const int bid = blockIdx.x;        // 512 = 16 g x 32 m
  const int g = bid & 15;
  const int m0 = (bid >> 4) * 128;
  const int n = g >> 2;
  const int kb = g & 3;
  const int o0 = n * 256;
  const int i0 = kb * 256;

  if (wave >= 4) {
    // ================= PRODUCER (waves 4,5 = 128 threads) =================
    const int grow = tid - 256;                    // row 0..127
    const float* px = xT + (size_t)i0 * B_ROWS + (m0 + grow);

    // phase 0 into buf 0
    {
      float x4[4];
#pragma unroll
      for (int c = 0; c < 4; ++c) x4[c] = px[(size_t)c * B_ROWS];
#pragma unroll
      for (int c = 0; c < 4; ++c) genH(x4[c], &As[0][c][grow][0]);
    }
    BAR();
#pragma unroll 1
    for (int p = 0; p < 64; ++p) {
      if (p < 63) {
        const int s1 = 4 * (p + 1);
        float x4[4];
#pragma unroll
        for (int c = 0; c < 4; ++c) x4[c] = px[(size_t)(s1 + c) * B_ROWS];
        _Float16* dstb = &As[(p & 1) ^ 1][0][grow][0];
#pragma unroll
        for (int c = 0; c < 4; ++c) genH(x4[c], dstb + c * (128 * ASTR));
      }
      BAR();
    }
    return;   // producers write no C
  }

  // ================== CONSUMER (waves 0..3 = 256 threads) ==================
  const int wc = wave;
  const int r32 = lane & 31, kh = lane >> 5;

  const _Float16* pb0 = Cw2 + ((size_t)(n * 8 + wc * 2 + 0) * 2048 + (size_t)i0 * 2) * 512 + lane * 8;
  const _Float16* pb1 = Cw2 + ((size_t)(n * 8 + wc * 2 + 1) * 2048 + (size_t)i0 * 2) * 512 + lane * 8;

  f32x16 acc[4][2];
#pragma unroll
  for (int fr = 0; fr < 4; ++fr)
#pragma unroll
    for (int fc = 0; fc < 2; ++fc)
#pragma unroll
      for (int q = 0; q < 16; ++q) acc[fr][fc][q] = 0.f;
  if (kb == 0) {
#pragma unroll
    for (int fc = 0; fc < 2; ++fc) {
      const float bv = bias[o0 + wc * 64 + fc * 32 + r32];
#pragma unroll
      for (int fr = 0; fr < 4; ++fr)
#pragma unroll
        for (int q = 0; q < 16; ++q) acc[fr][fc][q] = bv;
    }
  }

  half8 B0[4], B1[4];
  auto loadB = [&](half8 (&Bt)[4], int s) {
    const size_t base = (size_t)(s * 2) * 512;
    Bt[0] = *(const half8*)(pb0 + base);
    Bt[1] = *(const half8*)(pb0 + base + 512);
    Bt[2] = *(const half8*)(pb1 + base);
    Bt[3] = *(const half8*)(pb1 + base + 512);
  };
  auto mfma_sub = [&](int buf, int col, const half8 (&Bt)[4]) {
    half8 a_[4][2];
#pragma unroll
    for (int fr = 0; fr < 4; ++fr)
#pragma unroll
      for (int kcl = 0; kcl < 2; ++kcl)
        a_[fr][kcl] = *(const half8*)&As[buf][col][fr * 32 + r32][(kcl * 2 + kh) * 8];
#pragma unroll
    for (int kcl = 0; kcl < 2; ++kcl)
#pragma unroll
      for (int fr = 0; fr < 4; ++fr)
#pragma unroll
        for (int fc = 0; fc < 2; ++fc)
          acc[fr][fc] = __builtin_amdgcn_mfma_f32_32x32x16_f16(
              a_[fr][kcl], Bt[fc * 2 + kcl], acc[fr][fc], 0, 0, 0);
  };

  loadB(B0, 0);
  BAR();

#pragma unroll 1
  for (int p = 0; p < 64; ++p) {
    const int buf = p & 1;
    const int s = 4 * p;
    loadB(B1, s + 1);
    mfma_sub(buf, 0, B0);
    loadB(B0, s + 2);
    mfma_sub(buf, 1, B1);
    loadB(B1, s + 3);
    mfma_sub(buf, 2, B0);
    if (p < 63) loadB(B0, s + 4);
    mfma_sub(buf, 3, B1);
    BAR();                       // lgkm-only; B loads stay in flight
  }

  // epilogue: C/D 32x32 layout col=lane&31, row=(q&3)+8*(q>>2)+4*(lane>>5)
  float* dst;
  if (ATOMIC) dst = out;
  else dst = (kb == 0) ? out : part + (size_t)(kb - 1) * (B_ROWS * O_COLS);
#pragma unroll
  for (int fr = 0; fr < 4; ++fr)
#pragma unroll
    for (int fc = 0; fc < 2; ++fc)
#pragma unroll
      for (int q = 0; q < 16; ++q) {
        const int row = m0 + fr * 32 + (q & 3) + 8 * (q >> 2) + 4 * kh;
        const int col = o0 + wc * 64 + fc * 32 + r32;
        if (ATOMIC) atomicAdd(&dst[(size_t)row * O_COLS + col], acc[fr][fc][q]);
        else dst[(size_t)row * O_COLS + col] = acc[fr][fc][q];
      }
}

// ---------------------------------------------------------------------------
// Fallback (ws too small): direct-coef 16x16x32 path (no workspace).
// ---------------------------------------------------------------------------
__global__ __launch_bounds__(512, 4)
void fourier_gemm_direct(const float* __restrict__ x, const float* __restrict__ coef,
                         float* __restrict__ out) {
  __shared__ _Float16 Asd[128 * 64];
  __shared__ _Float16 Bsd[128 * 64];

  const int tid = threadIdx.x;
  const int lane = tid & 63;
  const int wave = tid >> 6;
  const int wr = wave >> 1;
  const int wcd = wave & 1;

  const int bid = blockIdx.x;
  const int o0 = (bid & 7) * 128;
  const int kb = (bid >> 3) & 1;
  const int m0 = (bid >> 4) * 128;

  const int rowA = tid >> 3;
  const int cch = tid & 7;
  const int cswz = cch ^ (rowA & 7);
  const int n1 = tid >> 3;
  const int c1q = tid & 7;
  const int r16 = lane & 15;
  const int kq = lane >> 4;

  float4v acc[2][4];
#pragma unroll
  for (int fr = 0; fr < 2; ++fr)
#pragma unroll
    for (int fc = 0; fc < 4; ++fc) acc[fr][fc] = (float4v){0.f, 0.f, 0.f, 0.f};

  float s1a[8], c1a[8], sa[8], ca[8];
  float s1b[8], c1b[8], sb[8], cb[8];

  const float* xa_base = x + (size_t)(m0 + rowA) * I_DIM + (size_t)kb * 512 + cch * 8;
  const float* xb_base = xa_base + (size_t)64 * I_DIM;

#pragma unroll 1
  for (int ib2 = 0; ib2 < 8; ++ib2) {
    {
      const float* xa = xa_base + ib2 * 64;
      const float* xb = xb_base + ib2 * 64;
      float xva[8], xvb[8];
      *(float4*)&xva[0] = *(const float4*)(xa);
      *(float4*)&xva[4] = *(const float4*)(xa + 4);
      *(float4*)&xvb[0] = *(const float4*)(xb);
      *(float4*)&xvb[4] = *(const float4*)(xb + 4);
#pragma unroll
      for (int e = 0; e < 8; ++e) {
        __sincosf(xva[e], &s1a[e], &c1a[e]); sa[e] = s1a[e]; ca[e] = c1a[e];
        __sincosf(xvb[e], &s1b[e], &c1b[e]); sb[e] = s1b[e]; cb[e] = c1b[e];
      }
    }
#pragma unroll 1
    for (int f = 0; f < NF33; ++f) {
      H8 ha, hb;
      if (f == 32) {
#pragma unroll
        for (int e = 0; e < 8; ++e) { ha.h[e] = (_Float16)1.0f; hb.h[e] = (_Float16)1.0f; }
      } else if ((f & 1) == 0) {
#pragma unroll
        for (int e = 0; e < 8; ++e) { ha.h[e] = (_Float16)sa[e]; hb.h[e] = (_Float16)sb[e]; }
      } else {
#pragma unroll
        for (int e = 0; e < 8; ++e) { ha.h[e] = (_Float16)ca[e]; hb.h[e] = (_Float16)cb[e]; }
      }
      __syncthreads();
      {
        const int ks = ksrc_of(f);
        const int ibg = kb * 8 + ib2;
        H8 b1, b2;
#pragma unroll
        for (int e = 0; e < 8; ++e) {
          const size_t ii = (size_t)(ibg * 64 + c1q * 8 + e) * NF33 + ks;
          b1.h[e] = (_Float16)coef[(size_t)(o0 + n1) * (I_DIM * NF33) + ii];
          b2.h[e] = (_Float16)coef[(size_t)(o0 + n1 + 64) * (I_DIM * NF33) + ii];
        }
        const int cs = (c1q ^ (n1 & 7)) << 3;
        *(half8*)&Bsd[n1 * 64 + cs] = b1.v;
        *(half8*)&Bsd[(n1 + 64) * 64 + cs] = b2.v;
      }
      *(half8*)&Asd[rowA * 64 + cswz * 8] = ha.v;
      *(half8*)&Asd[(rowA + 64) * 64 + cswz * 8] = hb.v;
      if ((f & 1) && (f + 2 < NF33)) {
#pragma unroll
        for (int e = 0; e < 8; ++e) {
          float ns = sa[e] * c1a[e] + ca[e] * s1a[e];
          ca[e] = ca[e] * c1a[e] - sa[e] * s1a[e]; sa[e] = ns;
          float nsb = sb[e] * c1b[e] + cb[e] * s1b[e];
          cb[e] = cb[e] * c1b[e] - sb[e] * s1b[e]; sb[e] = nsb;
        }
      }
      __syncthreads();
#pragma unroll
      for (int ksu = 0; ksu < 2; ++ksu) {
        const int ch = ((ksu << 2) + kq) ^ (r16 & 7);
        half8 af[2], bf[4];
#pragma unroll
        for (int fr = 0; fr < 2; ++fr)
          af[fr] = *(const half8*)&Asd[(wr * 32 + fr * 16 + r16) * 64 + ch * 8];
#pragma unroll
        for (int fc = 0; fc < 4; ++fc)
          bf[fc] = *(const half8*)&Bsd[(wcd * 64 + fc * 16 + r16) * 64 + ch * 8];
#pragma unroll
        for (int fr = 0; fr < 2; ++fr)
#pragma unroll
          for (int fc = 0; fc < 4; ++fc)
            acc[fr][fc] = __builtin_amdgcn_mfma_f32_16x16x32_f16(
                af[fr], bf[fc], acc[fr][fc], 0, 0, 0);
      }
    }
  }
#pragma unroll
  for (int fr = 0; fr < 2; ++fr)
#pragma unroll
    for (int fc = 0; fc < 4; ++fc)
#pragma unroll
      for (int r = 0; r < 4; ++r) {
        const int row = m0 + wr * 32 + fr * 16 + kq * 4 + r;
        const int col = o0 + wcd * 64 + fc * 16 + r16;
        atomicAdd(&out[(size_t)row * O_COLS + col], acc[fr][fc][r]);
      }
}

extern "C" void kernel_launch(void* const* d_in, const int* in_sizes, int n_in,
                              void* d_out, int out_size, void* d_ws, size_t ws_size,
                              hipStream_t stream) {
  const float* x = (const float*)d_in[0];
  const float* coef = (const float*)d_in[1];
  float* out = (float*)d_out;

  if (ws_size >= NEED_T1 || ws_size >= NEED_T2) {
    _Float16* Cw2 = (_Float16*)d_ws;
    float* xT   = (float*)((char*)d_ws + XT_OFF);
    float* bk   = (float*)((char*)d_ws + BK_OFF);
    float* bias = (float*)((char*)d_ws + BIAS_OFF);
    convert_coef2<<<dim3(4096), dim3(256), 0, stream>>>(coef, Cw2, bk);
    transpose_x<<<dim3(16, 64), dim3(256), 0, stream>>>(x, xT);
    bias_from_bk<<<dim3(4), dim3(256), 0, stream>>>(bk, bias);
    if (ws_size >= NEED_T1) {
      float* part = (float*)((char*)d_ws + PART_OFF);
      fourier_gemm10<false><<<dim3(512), dim3(384), 0, stream>>>(xT, Cw2, bias, out, part);
      reduce_parts<<<dim3(4096), dim3(256), 0, stream>>>(
          out, part, part + (size_t)B_ROWS * O_COLS, part + (size_t)2 * B_ROWS * O_COLS);
    } else {
      hipMemsetAsync(out, 0, (size_t)B_ROWS * O_COLS * sizeof(float), stream);
      fourier_gemm10<true><<<dim3(512), dim3(384), 0, stream>>>(xT, Cw2, bias, out, nullptr);
    }
  } else {
    hipMemsetAsync(out, 0, (size_t)B_ROWS * O_COLS * sizeof(float), stream);
    fourier_gemm_direct<<<dim3(512), dim3(512), 0, stream>>>(x, coef, out);
  }
}

// Round 13
// 422.259 us; speedup vs baseline: 1.0980x; 1.0980x over previous
//
#include <hip/hip_runtime.h>

// CustomFourierLayer: out[b,o] = sum_{i,k} coef[o,i,k] * f_k(x[b,i])
// R13: demand reduction on the R9 structure. BN=512 (8 col-wave-groups,
// wave = 128x64 = fr4 x fc2, same regs as R9) halves A-gen VALU
// (duplication x4 -> x2: 1 genH/thread/phase); genH STAGGERED by wave
// pair (gslot = wave>>1) so VALU overlaps other waves' MFMA instead of
// forming a phase-wide VALU-only region. Grid 256 = 32m x 8g, bid%8=g
// -> each XCD's L2 owns one (n,kb) B-stream. Phase = 4 i-cols, lgkm-only
// barrier, B frag-blobs global->VGPR crossing barriers, split-K x4.

#define O_COLS 1024
#define I_DIM  1024
#define NF33   33
#define B_ROWS 4096

#define CW2_BYTES  ((size_t)32 * 2048 * 512 * 2)   // 64 MiB, f16 frag blobs
#define XT_OFF     (CW2_BYTES)                      // 16 MiB f32 x^T
#define XT_BYTES   ((size_t)I_DIM * B_ROWS * 4)
#define BK_OFF     (XT_OFF + XT_BYTES)              // 4 MiB f32 bk32[i][o]
#define BK_BYTES   ((size_t)I_DIM * O_COLS * 4)
#define BIAS_OFF   (BK_OFF + BK_BYTES)              // 4 KiB
#define PART_OFF   (BIAS_OFF + (1 << 20))           // 3 x 16 MiB partials
#define PART_BYTES ((size_t)B_ROWS * O_COLS * 4)
#define NEED_T1    (PART_OFF + 3 * PART_BYTES)
#define NEED_T2    (BIAS_OFF + 4096)

#define ASTR 36    // A LDS row stride in f16 (72 B; 2-way bank aliasing = free)

typedef _Float16 half8 __attribute__((ext_vector_type(8)));
typedef float f32x16 __attribute__((ext_vector_type(16)));
typedef float float4v __attribute__((ext_vector_type(4)));
union H8 { half8 v; _Float16 h[8]; };

#define BAR() asm volatile("s_waitcnt lgkmcnt(0)\n\ts_barrier" ::: "memory")

// source k in coef's [sin1..16 | cos1..16 | 1] layout for interleaved feature f
__device__ __forceinline__ int ksrc_of(int f) {
  return (f >= 32) ? 32 : ((f >> 1) + ((f & 1) ? 16 : 0));
}

// ---------------------------------------------------------------------------
// coef f32 [o][i][k] -> Cw2 f16 in 32x32x16 B-fragment blobs + bk32[i][o]=k32.
// Blob (ob32, i*2+kcl) = 1KB: lane l = kh*32 + (o&31) holds 8 f16 = features
// kcl*16 + kh*8 + e of column i, output col o = ob32*32 + (l&31). (validated)
// ---------------------------------------------------------------------------
__global__ __launch_bounds__(256)
void convert_coef2(const float* __restrict__ coef, _Float16* __restrict__ Cw2,
                   float* __restrict__ bk) {
  const int gtid = blockIdx.x * 256 + threadIdx.x;   // 1M threads
  const int o = gtid & 1023;
  const int i = gtid >> 10;

  const float* src = coef + (size_t)o * (I_DIM * NF33) + (size_t)i * NF33;
  float r[NF33];
#pragma unroll
  for (int k = 0; k < NF33; ++k) r[k] = src[k];

  const int ob32 = o >> 5;
#pragma unroll
  for (int kcl = 0; kcl < 2; ++kcl) {
#pragma unroll
    for (int kh = 0; kh < 2; ++kh) {
      H8 h;
#pragma unroll
      for (int e = 0; e < 8; ++e)
        h.h[e] = (_Float16)r[ksrc_of(kcl * 16 + kh * 8 + e)];
      const size_t blob = (size_t)ob32 * 2048 + (size_t)i * 2 + kcl;
      *(half8*)(Cw2 + blob * 512 + (kh * 32 + (o & 31)) * 8) = h.v;
    }
  }
  bk[(size_t)i * 1024 + o] = r[32];
}

// x [4096][1024] -> xT [1024][4096]
__global__ __launch_bounds__(256)
void transpose_x(const float* __restrict__ x, float* __restrict__ xT) {
  __shared__ float t[64][65];
  const int bi = blockIdx.x;   // I-tile 0..15
  const int bj = blockIdx.y;   // B-tile 0..63
  const int tx = threadIdx.x & 63, ty = threadIdx.x >> 6;
#pragma unroll
  for (int mq = 0; mq < 16; ++mq) {
    const int r = mq * 4 + ty;
    t[r][tx] = x[(size_t)(bj * 64 + r) * I_DIM + bi * 64 + tx];
  }
  __syncthreads();
#pragma unroll
  for (int mq = 0; mq < 16; ++mq) {
    const int r = mq * 4 + ty;
    xT[(size_t)(bi * 64 + r) * B_ROWS + bj * 64 + tx] = t[tx][r];
  }
}

// bias[o] = sum_i bk[i][o]
__global__ __launch_bounds__(256)
void bias_from_bk(const float* __restrict__ bk, float* __restrict__ bias) {
  const int o = blockIdx.x * 256 + threadIdx.x;
  float s0 = 0.f, s1 = 0.f, s2 = 0.f, s3 = 0.f;
  for (int i = 0; i < 1024; i += 4) {
    s0 += bk[(size_t)i * 1024 + o];
    s1 += bk[(size_t)(i + 1) * 1024 + o];
    s2 += bk[(size_t)(i + 2) * 1024 + o];
    s3 += bk[(size_t)(i + 3) * 1024 + o];
  }
  bias[o] = (s0 + s1) + (s2 + s3);
}

// out += p0 + p1 + p2
__global__ __launch_bounds__(256)
void reduce_parts(float* __restrict__ out, const float* __restrict__ p0,
                  const float* __restrict__ p1, const float* __restrict__ p2) {
  const size_t i = ((size_t)blockIdx.x * 256 + threadIdx.x) * 4;
  float4v a = *(float4v*)(out + i);
  float4v b = *(const float4v*)(p0 + i);
  float4v c = *(const float4v*)(p1 + i);
  float4v d = *(const float4v*)(p2 + i);
  *(float4v*)(out + i) = a + b + c + d;
}

// doubling-tree harmonics 1..16 of xv -> 32 interleaved [sin,cos] f16 at dst
__device__ __forceinline__ void genH(float xv, _Float16* dst) {
  float S[17], C[17];
  __sincosf(xv, &S[1], &C[1]);
  S[2] = 2.f * S[1] * C[1];  C[2] = fmaf(-2.f * S[1], S[1], 1.f);
  S[3] = S[2] * C[1] + C[2] * S[1];  C[3] = C[2] * C[1] - S[2] * S[1];
  S[4] = 2.f * S[2] * C[2];  C[4] = fmaf(-2.f * S[2], S[2], 1.f);
  S[5] = S[4] * C[1] + C[4] * S[1];  C[5] = C[4] * C[1] - S[4] * S[1];
  S[6] = S[4] * C[2] + C[4] * S[2];  C[6] = C[4] * C[2] - S[4] * S[2];
  S[7] = S[4] * C[3] + C[4] * S[3];  C[7] = C[4] * C[3] - S[4] * S[3];
  S[8] = 2.f * S[4] * C[4];  C[8] = fmaf(-2.f * S[4], S[4], 1.f);
#pragma unroll
  for (int k = 1; k < 8; ++k) {
    S[8 + k] = S[8] * C[k] + C[8] * S[k];
    C[8 + k] = C[8] * C[k] - S[8] * S[k];
  }
  S[16] = 2.f * S[8] * C[8];  C[16] = fmaf(-2.f * S[8], S[8], 1.f);
#pragma unroll
  for (int c4 = 0; c4 < 4; ++c4) {
    H8 h;
#pragma unroll
    for (int q = 0; q < 4; ++q) {
      const int k = c4 * 4 + q + 1;
      h.h[2 * q] = (_Float16)S[k];  h.h[2 * q + 1] = (_Float16)C[k];
    }
    *(half8*)(dst + c4 * 8) = h.v;
  }
}

// ---------------------------------------------------------------------------
// GEMM: 512 threads = 8 waves; wave w covers cols o0 + w*64 (fc=2), all
// 128 rows (fr=4). BM=128, BN=512, 32x32x16 f16 MFMA, split-K x4.
// Phase = 4 i-cols; A generated once per block into LDS (dbuf), genH
// staggered by wave pair; one lgkm-only barrier per phase.
// ---------------------------------------------------------------------------
template <bool ATOMIC>
__global__ __launch_bounds__(512, 2)
void fourier_gemm11(const float* __restrict__ xT, const _Float16* __restrict__ Cw2,
                    const float* __restrict__ bias, float* __restrict__ out,
                    float* __restrict__ part) {
  __shared__ _Float16 As[2][4][128][ASTR];   // [buf][col][row][36], 73.7 KB

  const int tid = threadIdx.x, lane = tid & 63, wave = tid >> 6;  // wave 0..7

  const int bid = blockIdx.x;        // 256 = 32 m x 8 g; bid%8 = g = XCD slot
  const int g = bid & 7;
  const int m0 = (bid >> 3) * 128;
  const int n = g & 1;
  const int kb = g >> 1;             // 0..3
  const int o0 = n * 512;
  const int i0 = kb * 256;

  const int r32 = lane & 31, kh = lane >> 5;
  const int gslot = wave >> 1;       // 0..3: which substep this wave's genH follows

  // A-gen assignment: thread owns (row = tid&127, col-in-phase = tid>>7)
  const int grow = tid & 127;
  const int gcol = tid >> 7;         // 0..3 (== gslot, uniform per wave)
  const float* px = xT + (size_t)(i0 + gcol) * B_ROWS + (m0 + grow);

  // B pointers: wave covers cols o0 + wave*64 + fc*32 -> ob32 = n*16+wave*2+fc
  const _Float16* pb0 = Cw2 + ((size_t)(n * 16 + wave * 2 + 0) * 2048 + (size_t)i0 * 2) * 512 + lane * 8;
  const _Float16* pb1 = Cw2 + ((size_t)(n * 16 + wave * 2 + 1) * 2048 + (size_t)i0 * 2) * 512 + lane * 8;

  f32x16 acc[4][2];
#pragma unroll
  for (int fr = 0; fr < 4; ++fr)
#pragma unroll
    for (int fc = 0; fc < 2; ++fc)
#pragma unroll
      for (int q = 0; q < 16; ++q) acc[fr][fc][q] = 0.f;
  if (kb == 0) {
#pragma unroll
    for (int fc = 0; fc < 2; ++fc) {
      const float bv = bias[o0 + wave * 64 + fc * 32 + r32];
#pragma unroll
      for (int fr = 0; fr < 4; ++fr)
#pragma unroll
        for (int q = 0; q < 16; ++q) acc[fr][fc][q] = bv;
    }
  }

  half8 B0[4], B1[4];
  auto loadB = [&](half8 (&Bt)[4], int s) {   // s = local substep index
    const size_t base = (size_t)(s * 2) * 512;
    Bt[0] = *(const half8*)(pb0 + base);
    Bt[1] = *(const half8*)(pb0 + base + 512);
    Bt[2] = *(const half8*)(pb1 + base);
    Bt[3] = *(const half8*)(pb1 + base + 512);
  };

  auto mfma_sub = [&](int buf, int col, const half8 (&Bt)[4]) {
    half8 a_[4][2];
#pragma unroll
    for (int fr = 0; fr < 4; ++fr)
#pragma unroll
      for (int kcl = 0; kcl < 2; ++kcl)
        a_[fr][kcl] = *(const half8*)&As[buf][col][fr * 32 + r32][(kcl * 2 + kh) * 8];
#pragma unroll
    for (int kcl = 0; kcl < 2; ++kcl)
#pragma unroll
      for (int fr = 0; fr < 4; ++fr)
#pragma unroll
        for (int fc = 0; fc < 2; ++fc)
          acc[fr][fc] = __builtin_amdgcn_mfma_f32_32x32x16_f16(
              a_[fr][kcl], Bt[fc * 2 + kcl], acc[fr][fc], 0, 0, 0);
  };

  // prologue: A for phase 0 into buf0 (1 genH/thread); B for substep 0
  genH(px[0], &As[0][gcol][grow][0]);
  float xa = px[(size_t)4 * B_ROWS];          // x for phase-1 gen
  loadB(B0, 0);
  BAR();

#pragma unroll 1
  for (int p = 0; p < 64; ++p) {
    const int buf = p & 1;
    const int s = 4 * p;
    // x for phase p+2 (OOB-safe: worst case lands inside d_ws)
    const float xan = px[(size_t)(s + 8) * B_ROWS];
    _Float16* gdst = &As[buf ^ 1][gcol][grow][0];

    loadB(B1, s + 1);
    mfma_sub(buf, 0, B0);
    if (gslot == 0) genH(xa, gdst);           // staggered A-gen for p+1
    loadB(B0, s + 2);
    mfma_sub(buf, 1, B1);
    if (gslot == 1) genH(xa, gdst);
    loadB(B1, s + 3);
    mfma_sub(buf, 2, B0);
    if (gslot == 2) genH(xa, gdst);
    if (p < 63) loadB(B0, s + 4);
    mfma_sub(buf, 3, B1);
    if (gslot == 3) genH(xa, gdst);
    BAR();                       // lgkm-only: B global loads stay in flight
    xa = xan;
  }

  // epilogue: C/D 32x32 layout col=lane&31, row=(q&3)+8*(q>>2)+4*(lane>>5)
  float* dst;
  if (ATOMIC) dst = out;
  else dst = (kb == 0) ? out : part + (size_t)(kb - 1) * (B_ROWS * O_COLS);
#pragma unroll
  for (int fr = 0; fr < 4; ++fr)
#pragma unroll
    for (int fc = 0; fc < 2; ++fc)
#pragma unroll
      for (int q = 0; q < 16; ++q) {
        const int row = m0 + fr * 32 + (q & 3) + 8 * (q >> 2) + 4 * kh;
        const int col = o0 + wave * 64 + fc * 32 + r32;
        if (ATOMIC) atomicAdd(&dst[(size_t)row * O_COLS + col], acc[fr][fc][q]);
        else dst[(size_t)row * O_COLS + col] = acc[fr][fc][q];
      }
}

// ---------------------------------------------------------------------------
// Fallback (ws too small): direct-coef 16x16x32 path (no workspace).
// ---------------------------------------------------------------------------
__global__ __launch_bounds__(512, 4)
void fourier_gemm_direct(const float* __restrict__ x, const float* __restrict__ coef,
                         float* __restrict__ out) {
  __shared__ _Float16 Asd[128 * 64];
  __shared__ _Float16 Bsd[128 * 64];

  const int tid = threadIdx.x;
  const int lane = tid & 63;
  const int wave = tid >> 6;
  const int wr = wave >> 1;
  const int wcd = wave & 1;

  const int bid = blockIdx.x;
  const int o0 = (bid & 7) * 128;
  const int kb = (bid >> 3) & 1;
  const int m0 = (bid >> 4) * 128;

  const int rowA = tid >> 3;
  const int cch = tid & 7;
  const int cswz = cch ^ (rowA & 7);
  const int n1 = tid >> 3;
  const int c1q = tid & 7;
  const int r16 = lane & 15;
  const int kq = lane >> 4;

  float4v acc[2][4];
#pragma unroll
  for (int fr = 0; fr < 2; ++fr)
#pragma unroll
    for (int fc = 0; fc < 4; ++fc) acc[fr][fc] = (float4v){0.f, 0.f, 0.f, 0.f};

  float s1a[8], c1a[8], sa[8], ca[8];
  float s1b[8], c1b[8], sb[8], cb[8];

  const float* xa_base = x + (size_t)(m0 + rowA) * I_DIM + (size_t)kb * 512 + cch * 8;
  const float* xb_base = xa_base + (size_t)64 * I_DIM;

#pragma unroll 1
  for (int ib2 = 0; ib2 < 8; ++ib2) {
    {
      const float* xa = xa_base + ib2 * 64;
      const float* xb = xb_base + ib2 * 64;
      float xva[8], xvb[8];
      *(float4*)&xva[0] = *(const float4*)(xa);
      *(float4*)&xva[4] = *(const float4*)(xa + 4);
      *(float4*)&xvb[0] = *(const float4*)(xb);
      *(float4*)&xvb[4] = *(const float4*)(xb + 4);
#pragma unroll
      for (int e = 0; e < 8; ++e) {
        __sincosf(xva[e], &s1a[e], &c1a[e]); sa[e] = s1a[e]; ca[e] = c1a[e];
        __sincosf(xvb[e], &s1b[e], &c1b[e]); sb[e] = s1b[e]; cb[e] = c1b[e];
      }
    }
#pragma unroll 1
    for (int f = 0; f < NF33; ++f) {
      H8 ha, hb;
      if (f == 32) {
#pragma unroll
        for (int e = 0; e < 8; ++e) { ha.h[e] = (_Float16)1.0f; hb.h[e] = (_Float16)1.0f; }
      } else if ((f & 1) == 0) {
#pragma unroll
        for (int e = 0; e < 8; ++e) { ha.h[e] = (_Float16)sa[e]; hb.h[e] = (_Float16)sb[e]; }
      } else {
#pragma unroll
        for (int e = 0; e < 8; ++e) { ha.h[e] = (_Float16)ca[e]; hb.h[e] = (_Float16)cb[e]; }
      }
      __syncthreads();
      {
        const int ks = ksrc_of(f);
        const int ibg = kb * 8 + ib2;
        H8 b1, b2;
#pragma unroll
        for (int e = 0; e < 8; ++e) {
          const size_t ii = (size_t)(ibg * 64 + c1q * 8 + e) * NF33 + ks;
          b1.h[e] = (_Float16)coef[(size_t)(o0 + n1) * (I_DIM * NF33) + ii];
          b2.h[e] = (_Float16)coef[(size_t)(o0 + n1 + 64) * (I_DIM * NF33) + ii];
        }
        const int cs = (c1q ^ (n1 & 7)) << 3;
        *(half8*)&Bsd[n1 * 64 + cs] = b1.v;
        *(half8*)&Bsd[(n1 + 64) * 64 + cs] = b2.v;
      }
      *(half8*)&Asd[rowA * 64 + cswz * 8] = ha.v;
      *(half8*)&Asd[(rowA + 64) * 64 + cswz * 8] = hb.v;
      if ((f & 1) && (f + 2 < NF33)) {
#pragma unroll
        for (int e = 0; e < 8; ++e) {
          float ns = sa[e] * c1a[e] + ca[e] * s1a[e];
          ca[e] = ca[e] * c1a[e] - sa[e] * s1a[e]; sa[e] = ns;
          float nsb = sb[e] * c1b[e] + cb[e] * s1b[e];
          cb[e] = cb[e] * c1b[e] - sb[e] * s1b[e]; sb[e] = nsb;
        }
      }
      __syncthreads();
#pragma unroll
      for (int ksu = 0; ksu < 2; ++ksu) {
        const int ch = ((ksu << 2) + kq) ^ (r16 & 7);
        half8 af[2], bf[4];
#pragma unroll
        for (int fr = 0; fr < 2; ++fr)
          af[fr] = *(const half8*)&Asd[(wr * 32 + fr * 16 + r16) * 64 + ch * 8];
#pragma unroll
        for (int fc = 0; fc < 4; ++fc)
          bf[fc] = *(const half8*)&Bsd[(wcd * 64 + fc * 16 + r16) * 64 + ch * 8];
#pragma unroll
        for (int fr = 0; fr < 2; ++fr)
#pragma unroll
          for (int fc = 0; fc < 4; ++fc)
            acc[fr][fc] = __builtin_amdgcn_mfma_f32_16x16x32_f16(
                af[fr], bf[fc], acc[fr][fc], 0, 0, 0);
      }
    }
  }
#pragma unroll
  for (int fr = 0; fr < 2; ++fr)
#pragma unroll
    for (int fc = 0; fc < 4; ++fc)
#pragma unroll
      for (int r = 0; r < 4; ++r) {
        const int row = m0 + wr * 32 + fr * 16 + kq * 4 + r;
        const int col = o0 + wcd * 64 + fc * 16 + r16;
        atomicAdd(&out[(size_t)row * O_COLS + col], acc[fr][fc][r]);
      }
}

extern "C" void kernel_launch(void* const* d_in, const int* in_sizes, int n_in,
                              void* d_out, int out_size, void* d_ws, size_t ws_size,
                              hipStream_t stream) {
  const float* x = (const float*)d_in[0];
  const float* coef = (const float*)d_in[1];
  float* out = (float*)d_out;

  if (ws_size >= NEED_T1 || ws_size >= NEED_T2) {
    _Float16* Cw2 = (_Float16*)d_ws;
    float* xT   = (float*)((char*)d_ws + XT_OFF);
    float* bk   = (float*)((char*)d_ws + BK_OFF);
    float* bias = (float*)((char*)d_ws + BIAS_OFF);
    convert_coef2<<<dim3(4096), dim3(256), 0, stream>>>(coef, Cw2, bk);
    transpose_x<<<dim3(16, 64), dim3(256), 0, stream>>>(x, xT);
    bias_from_bk<<<dim3(4), dim3(256), 0, stream>>>(bk, bias);
    if (ws_size >= NEED_T1) {
      float* part = (float*)((char*)d_ws + PART_OFF);
      fourier_gemm11<false><<<dim3(256), dim3(512), 0, stream>>>(xT, Cw2, bias, out, part);
      reduce_parts<<<dim3(4096), dim3(256), 0, stream>>>(
          out, part, part + (size_t)B_ROWS * O_COLS, part + (size_t)2 * B_ROWS * O_COLS);
    } else {
      hipMemsetAsync(out, 0, (size_t)B_ROWS * O_COLS * sizeof(float), stream);
      fourier_gemm11<true><<<dim3(256), dim3(512), 0, stream>>>(xT, Cw2, bias, out, nullptr);
    }
  } else {
    hipMemsetAsync(out, 0, (size_t)B_ROWS * O_COLS * sizeof(float), stream);
    fourier_gemm_direct<<<dim3(512), dim3(512), 0, stream>>>(x, coef, out);
  }
}